// Round 5
// baseline (613.823 us; speedup 1.0000x reference)
//
#include <hip/hip_runtime.h>
#include <hip/hip_bf16.h>
#include <stdint.h>

#define N_PTS 400000
#define K_TAPS 9
#define CIN 128
#define COUT 128
#define EPS_BN 1e-4f
#define LEAK 0.333f

typedef __bf16 bf16x8 __attribute__((ext_vector_type(8)));
typedef float floatx16 __attribute__((ext_vector_type(16)));
typedef float f32x4 __attribute__((ext_vector_type(4)));  // clang vector: ok for nontemporal builtins

// ws layout (bytes):
//   [0, 294912)              packed W (bf16) in B-fragment order
//   [294912, 295424)         gsum[128]   (float)
//   [295424, 295936)         gsumsq[128] (float)
//   [295936, 296960)         (pad)
//   -- Path A only --
//   [296960, ...)            feats_bf16 [N+1,128]  (row N_PTS = zeros, sentinel target)
//   [...,    ...)            prebn_bf16 [N,128]
#define PACKW_BYTES (K_TAPS * 8 * 4 * 64 * 8 * 2)  // 294912 (32768 B per tap)
#define SUMS_OFF PACKW_BYTES
#define SUMSQ_OFF (SUMS_OFF + 512)
#define AB_OFF (SUMSQ_OFF + 512)
#define FEATSB_OFF (AB_OFF + 1024)                               // 296960
#define PREBN_OFF (FEATSB_OFF + (size_t)(N_PTS + 1) * CIN * 2)   // feats + zero row
#define WS_NEED_A (PREBN_OFF + (size_t)N_PTS * COUT * 2)

// round-to-nearest (half away) fp32 -> bf16, packed pair
__device__ inline unsigned int pack_bf16_rn(float lo, float hi) {
    unsigned int a = __float_as_uint(lo) + 0x8000u;
    unsigned int b = __float_as_uint(hi) + 0x8000u;
    return (a >> 16) | (b & 0xffff0000u);
}

// async global->LDS, 16B per lane. LDS dest is wave-uniform base + lane*16.
__device__ inline void gload_lds16(const void* g, void* l) {
    __builtin_amdgcn_global_load_lds(
        (const __attribute__((address_space(1))) unsigned int*)g,
        (__attribute__((address_space(3))) unsigned int*)l, 16, 0, 0);
}

// fp32 feats -> bf16 (rn), 16 elems/thread. Extra block zeroes the sentinel row.
__global__ __launch_bounds__(256) void convert_feats_kernel(
    const float* __restrict__ f, __hip_bfloat16* __restrict__ o) {
    if (blockIdx.x == 12500) {  // zero row at index N_PTS (gather target for missing nbrs)
        if (threadIdx.x < 16) {
            uint4 z = {0u, 0u, 0u, 0u};
            *(uint4*)(o + (size_t)N_PTS * CIN + threadIdx.x * 8) = z;
        }
        return;
    }
    size_t i = ((size_t)blockIdx.x * 256 + threadIdx.x) * 16;
    const float4* f4 = (const float4*)(f + i);
    float4 a = f4[0], b = f4[1], c = f4[2], d = f4[3];
    uint4 v0, v1;
    v0.x = pack_bf16_rn(a.x, a.y);
    v0.y = pack_bf16_rn(a.z, a.w);
    v0.z = pack_bf16_rn(b.x, b.y);
    v0.w = pack_bf16_rn(b.z, b.w);
    v1.x = pack_bf16_rn(c.x, c.y);
    v1.y = pack_bf16_rn(c.z, c.w);
    v1.z = pack_bf16_rn(d.x, d.y);
    v1.w = pack_bf16_rn(d.z, d.w);
    *(uint4*)(o + i) = v0;
    *(uint4*)(o + i + 8) = v1;
}

// Pack W[k][ci][co] (fp32) into bf16 MFMA B-fragment order:
// packw[frag=((k*8+c)*4+t)][lane*8+j] = W[k][c*16 + (lane>>5)*8 + j][t*32 + (lane&31)]
// Block 288 zeroes gsum[128]+gsumsq[128].
__global__ void pack_w_kernel(const float* __restrict__ W,
                              __hip_bfloat16* __restrict__ pw,
                              float* __restrict__ gsum) {
    if (blockIdx.x == 288) {
        ((float4*)gsum)[threadIdx.x] = make_float4(0.f, 0.f, 0.f, 0.f);
        return;
    }
    int frag = blockIdx.x;  // 0..287
    int lane = threadIdx.x; // 0..63
    int t = frag & 3;
    int c = (frag >> 2) & 7;
    int k = frag >> 5;
    int n = lane & 31;
    int kk0 = (lane >> 5) * 8;
    const float* src = W + (size_t)k * CIN * COUT + (size_t)(c * 16 + kk0) * COUT + (t * 32 + n);
    __hip_bfloat16* dst = pw + (size_t)frag * 512 + lane * 8;
#pragma unroll
    for (int j = 0; j < 8; ++j) dst[j] = (__hip_bfloat16)src[(size_t)j * COUT];
}

// Stage one tap's packed W (32 KB) into LDS buffer buf via async global_load_lds.
// 8 waves x 4 chunks x (64 lanes x 16B) = 32 KB, linear layout.
__device__ inline void stage_tap(char* smem, const char* pwb, int k, int buf,
                                 int wave, int lane) {
    const char* g = pwb + (size_t)k * 32768;
    char* l = smem + buf * 32768;
#pragma unroll
    for (int i = 0; i < 4; ++i) {
        int chunk = i * 8 + wave;
        gload_lds16(g + (size_t)chunk * 1024 + (size_t)lane * 16, l + (size_t)chunk * 1024);
    }
}

// Main gather-GEMM. Grid: 1563 x 512. WG tile: 256 rows x 128 cout (8 waves).
// Wave w: rows [blk*256 + w*32, +32) x 128 cout via 4 n-tiles of 32x32x16 MFMA.
//
// Counted-vmcnt pipeline (bf16 path), per tap k:
//   [load nb(k+2): 1 vmem]  [stage W(k+1): 4 global_load_lds]  (sched fence)
//   [32 MFMA over tap k, interleaved with 8 in-place gathers of tap k+1's A rows]
//   (sched fence)  s_waitcnt vmcnt(8)  -> nb+stage retired, 8 gathers STAY IN FLIGHT
//   s_barrier      -> W(k+1) visible to all waves; gathers complete under next MFMAs.
// No vmcnt(0) drain in the loop (T4); av[] reused in place (no reg growth, no spill).
// Missing neighbors gather from the zeroed sentinel row (no cndmask in inner loop).
template <bool GATHER_BF16, bool OUT_BF16>
__global__ __launch_bounds__(512, 4) void spconv_gemm_kernel(
    const void* __restrict__ feats_any,
    const __hip_bfloat16* __restrict__ packw,
    const int* __restrict__ neigh,
    void* __restrict__ out_any,
    float* __restrict__ gsum, float* __restrict__ gsumsq) {
    __shared__ __align__(16) char smem[65536];

    const int tid = threadIdx.x;
    const int wave = tid >> 6;
    const int lane = tid & 63;
    const int hj = lane >> 5;
    const int m = lane & 31;
    const int row = blockIdx.x * 256 + wave * 32 + m;
    const bool rvalid = (row < N_PTS);
    const size_t nbase = (size_t)row * K_TAPS;

    floatx16 acc[4];
#pragma unroll
    for (int t = 0; t < 4; ++t)
#pragma unroll
        for (int r = 0; r < 16; ++r) acc[t][r] = 0.0f;

    const char* pwb = (const char*)packw;

    if constexpr (GATHER_BF16) {
        const __hip_bfloat16* fb = (const __hip_bfloat16*)feats_any;
        uint4 av[8];     // A fragments of the CURRENT tap; overwritten in place for next
        int nbA, nbB;    // rolling neighbor ids: slot (k&1) holds nb[k]

        // prologue: nb[0], nb[1]; stage W(0); gather tap-0 A; counted wait; barrier
        nbA = rvalid ? neigh[nbase + 0] : N_PTS;
        nbB = rvalid ? neigh[nbase + 1] : N_PTS;
        stage_tap(smem, pwb, 0, 0, wave, lane);
        __builtin_amdgcn_sched_barrier(0);
        {
            const uint4* ar = (const uint4*)(fb + (size_t)nbA * CIN);
#pragma unroll
            for (int c = 0; c < 8; ++c) av[c] = ar[c * 2 + hj];
        }
        __builtin_amdgcn_sched_barrier(0);
        asm volatile("s_waitcnt vmcnt(8)" ::: "memory");  // nb+stage done; gathers fly
        __builtin_amdgcn_s_barrier();

#pragma unroll
        for (int k = 0; k < K_TAPS; ++k) {
            const int cur = k & 1;
            // rolling nb prefetch for tap k+2 into the slot of (dead) nb[k]
            if (k + 2 < K_TAPS) {
                int v = rvalid ? neigh[nbase + k + 2] : N_PTS;
                if (cur == 0) nbA = v; else nbB = v;
            }
            if (k + 1 < K_TAPS) stage_tap(smem, pwb, k + 1, cur ^ 1, wave, lane);
            __builtin_amdgcn_sched_barrier(0);

            const char* bbase = smem + (size_t)cur * 32768;
            const int nbn = (cur == 0) ? nbB : nbA;  // nb[k+1]
            const uint4* arn = (const uint4*)(fb + (size_t)nbn * CIN);

            __builtin_amdgcn_s_setprio(1);
#pragma unroll
            for (int c = 0; c < 8; ++c) {
                bf16x8 afrag = __builtin_bit_cast(bf16x8, av[c]);
#pragma unroll
                for (int t = 0; t < 4; ++t) {
                    bf16x8 bfrag = __builtin_bit_cast(
                        bf16x8, *(const uint4*)(bbase + (c * 4 + t) * 1024 + lane * 16));
                    acc[t] = __builtin_amdgcn_mfma_f32_32x32x16_bf16(afrag, bfrag, acc[t], 0, 0, 0);
                }
                if (k + 1 < K_TAPS) av[c] = arn[c * 2 + hj];  // in-place prefetch, tap k+1
            }
            __builtin_amdgcn_s_setprio(0);
            __builtin_amdgcn_sched_barrier(0);

            if (k + 1 < K_TAPS) {
                // retire nb(k+2)+stage(k+1) (oldest 5); the 8 gathers of tap k+1 remain
                // outstanding ACROSS the barrier and finish under the next MFMA phase.
                asm volatile("s_waitcnt vmcnt(8)" ::: "memory");
                __builtin_amdgcn_s_barrier();
            }
        }
    } else {
        // fp32 fallback path (round-1 structure: gather in-tap, full barriers)
        int nb[K_TAPS];
#pragma unroll
        for (int k = 0; k < K_TAPS; ++k)
            nb[k] = rvalid ? neigh[nbase + k] : N_PTS;
        stage_tap(smem, pwb, 0, 0, wave, lane);
        __syncthreads();
#pragma unroll
        for (int k = 0; k < K_TAPS; ++k) {
            const int cur = k & 1;
            const bool valid = (nb[k] < N_PTS);
            const int safe = valid ? nb[k] : 0;
            uint4 a8[8];
            const float4* ar = (const float4*)((const float*)feats_any + (size_t)safe * CIN);
#pragma unroll
            for (int c = 0; c < 8; ++c) {
                float4 f0 = ar[c * 4 + hj * 2];
                float4 f1 = ar[c * 4 + hj * 2 + 1];
                a8[c].x = pack_bf16_rn(f0.x, f0.y);
                a8[c].y = pack_bf16_rn(f0.z, f0.w);
                a8[c].z = pack_bf16_rn(f1.x, f1.y);
                a8[c].w = pack_bf16_rn(f1.z, f1.w);
            }
            if (k + 1 < K_TAPS) stage_tap(smem, pwb, k + 1, cur ^ 1, wave, lane);
            if (!valid) {
#pragma unroll
                for (int c = 0; c < 8; ++c) { a8[c].x = 0u; a8[c].y = 0u; a8[c].z = 0u; a8[c].w = 0u; }
            }
            const char* bbase = smem + (size_t)cur * 32768;
#pragma unroll
            for (int c = 0; c < 8; ++c) {
                bf16x8 afrag = __builtin_bit_cast(bf16x8, a8[c]);
#pragma unroll
                for (int t = 0; t < 4; ++t) {
                    bf16x8 bfrag = __builtin_bit_cast(
                        bf16x8, *(const uint4*)(bbase + (c * 4 + t) * 1024 + lane * 16));
                    acc[t] = __builtin_amdgcn_mfma_f32_32x32x16_bf16(afrag, bfrag, acc[t], 0, 0, 0);
                }
            }
            __syncthreads();
        }
    }

    __syncthreads();  // full drain; smem reused below

    // ---- epilogue: store pre-BN, accumulate channel sums ----
    // C/D layout (32x32): col = lane&31, row = (reg&3) + 8*(reg>>2) + 4*(lane>>5)
#pragma unroll
    for (int t = 0; t < 4; ++t) {
#pragma unroll
        for (int r = 0; r < 16; ++r) {
            int row_local = (r & 3) + 8 * (r >> 2) + 4 * hj;
            size_t grow = (size_t)blockIdx.x * 256 + wave * 32 + row_local;
            if (grow < N_PTS) {
                if (OUT_BF16)
                    ((__hip_bfloat16*)out_any)[grow * COUT + (t * 32 + m)] =
                        (__hip_bfloat16)acc[t][r];
                else
                    ((float*)out_any)[grow * COUT + (t * 32 + m)] = acc[t][r];
            }
        }
    }

    float s[4], q[4];
#pragma unroll
    for (int t = 0; t < 4; ++t) {
        s[t] = 0.0f; q[t] = 0.0f;
#pragma unroll
        for (int r = 0; r < 16; ++r) {
            float v = acc[t][r];
            s[t] += v;
            q[t] += v * v;
        }
        s[t] += __shfl_xor(s[t], 32, 64);
        q[t] += __shfl_xor(q[t], 32, 64);
    }

    float* lsum = (float*)smem;           // [8][128]
    float* lsq = (float*)(smem + 4096);   // [8][128]
    if (hj == 0) {
#pragma unroll
        for (int t = 0; t < 4; ++t) {
            lsum[wave * 128 + t * 32 + m] = s[t];
            lsq[wave * 128 + t * 32 + m] = q[t];
        }
    }
    __syncthreads();
    if (tid < 128) {
        float ts = 0.0f, tq = 0.0f;
#pragma unroll
        for (int w = 0; w < 8; ++w) {
            ts += lsum[w * 128 + tid];
            tq += lsq[w * 128 + tid];
        }
        atomicAdd(&gsum[tid], ts);
        atomicAdd(&gsumsq[tid], tq);
    }
}

// Path A BN: per-block ab in LDS (folds finalize_scales), 16 elems/thread.
// `out` is write-once/never-read -> nontemporal stores (clang ext_vector type).
__global__ __launch_bounds__(256) void bn_lrelu_bf16_kernel(
    const __hip_bfloat16* __restrict__ pre, float* __restrict__ out,
    const float* __restrict__ gsum, const float* __restrict__ gsumsq,
    const float* __restrict__ gamma, const float* __restrict__ beta) {
    __shared__ float ab[256];
    const int tid = threadIdx.x;
    if (tid < 128) {
        const float inv_n = 1.0f / (float)N_PTS;
        float mean = gsum[tid] * inv_n;
        float var = gsumsq[tid] * inv_n - mean * mean;
        float a = gamma[tid] * rsqrtf(var + EPS_BN);
        ab[tid] = a;
        ab[128 + tid] = beta[tid] - mean * a;
    }
    __syncthreads();

    size_t i = ((size_t)blockIdx.x * 256 + tid) * 16;
    int c0 = (int)(i & (COUT - 1));
    uint4 v0 = *(const uint4*)(pre + i);
    uint4 v1 = *(const uint4*)(pre + i + 8);
    unsigned int u[8] = {v0.x, v0.y, v0.z, v0.w, v1.x, v1.y, v1.z, v1.w};
    float o[16];
#pragma unroll
    for (int w = 0; w < 8; ++w) {
        float x0 = __uint_as_float((u[w] & 0xffffu) << 16);
        float x1 = __uint_as_float((u[w] >> 16) << 16);
        int c = c0 + 2 * w;
        float y0 = fmaf(ab[c], x0, ab[128 + c]);
        float y1 = fmaf(ab[c + 1], x1, ab[128 + c + 1]);
        o[2 * w] = (y0 > 0.0f) ? y0 : LEAK * y0;
        o[2 * w + 1] = (y1 > 0.0f) ? y1 : LEAK * y1;
    }
#pragma unroll
    for (int w = 0; w < 4; ++w) {
        f32x4 vv = {o[4 * w], o[4 * w + 1], o[4 * w + 2], o[4 * w + 3]};
        __builtin_nontemporal_store(vv, (f32x4*)(out + i + 4 * w));
    }
}

// Path B: in-place fp32 BN + LeakyReLU, 8 elems/thread, per-block ab.
__global__ __launch_bounds__(256) void bn_lrelu_f32_kernel(
    float* __restrict__ out,
    const float* __restrict__ gsum, const float* __restrict__ gsumsq,
    const float* __restrict__ gamma, const float* __restrict__ beta) {
    __shared__ float ab[256];
    const int tid = threadIdx.x;
    if (tid < 128) {
        const float inv_n = 1.0f / (float)N_PTS;
        float mean = gsum[tid] * inv_n;
        float var = gsumsq[tid] * inv_n - mean * mean;
        float a = gamma[tid] * rsqrtf(var + EPS_BN);
        ab[tid] = a;
        ab[128 + tid] = beta[tid] - mean * a;
    }
    __syncthreads();

    size_t i = ((size_t)blockIdx.x * 256 + tid) * 8;
    int c0 = (int)(i & (COUT - 1));
#pragma unroll
    for (int h = 0; h < 2; ++h) {
        float4 v = *(const float4*)(out + i + 4 * h);
        int c = c0 + 4 * h;
        v.x = fmaf(ab[c], v.x, ab[128 + c]);
        v.y = fmaf(ab[c + 1], v.y, ab[128 + c + 1]);
        v.z = fmaf(ab[c + 2], v.z, ab[128 + c + 2]);
        v.w = fmaf(ab[c + 3], v.w, ab[128 + c + 3]);
        v.x = (v.x > 0.0f) ? v.x : LEAK * v.x;
        v.y = (v.y > 0.0f) ? v.y : LEAK * v.y;
        v.z = (v.z > 0.0f) ? v.z : LEAK * v.z;
        v.w = (v.w > 0.0f) ? v.w : LEAK * v.w;
        *(float4*)(out + i + 4 * h) = v;
    }
}

extern "C" void kernel_launch(void* const* d_in, const int* in_sizes, int n_in,
                              void* d_out, int out_size, void* d_ws, size_t ws_size,
                              hipStream_t stream) {
    const float* feats = (const float*)d_in[0];
    const float* W = (const float*)d_in[1];
    // d_in[2] = bias: cancels exactly under BatchNorm (out - mean removes per-channel constants)
    const float* gamma = (const float*)d_in[3];
    const float* beta = (const float*)d_in[4];
    const int* neigh = (const int*)d_in[5];
    float* out = (float*)d_out;

    char* ws = (char*)d_ws;
    __hip_bfloat16* packw = (__hip_bfloat16*)ws;
    float* gsum = (float*)(ws + SUMS_OFF);
    float* gsumsq = (float*)(ws + SUMSQ_OFF);

    const int gemm_grid = (N_PTS + 255) / 256;  // 1563 (tail rows guarded)

    // pack_w grid 289: blocks 0..287 pack W, block 288 zeroes gsum+gsumsq
    hipLaunchKernelGGL(pack_w_kernel, dim3(289), dim3(64), 0, stream, W, packw, gsum);

    if (ws_size >= WS_NEED_A) {
        __hip_bfloat16* featsb = (__hip_bfloat16*)(ws + FEATSB_OFF);
        __hip_bfloat16* prebn = (__hip_bfloat16*)(ws + PREBN_OFF);
        // grid 12501: block 12500 zeroes the sentinel row N_PTS
        hipLaunchKernelGGL(convert_feats_kernel, dim3(12501), dim3(256), 0, stream, feats, featsb);
        hipLaunchKernelGGL((spconv_gemm_kernel<true, true>), dim3(gemm_grid), dim3(512), 0,
                           stream, (const void*)featsb, packw, neigh, (void*)prebn, gsum, gsumsq);
        hipLaunchKernelGGL(bn_lrelu_bf16_kernel, dim3(12500), dim3(256), 0, stream,
                           prebn, out, gsum, gsumsq, gamma, beta);
    } else {
        hipLaunchKernelGGL((spconv_gemm_kernel<false, false>), dim3(gemm_grid), dim3(512), 0,
                           stream, (const void*)feats, packw, neigh, (void*)out, gsum, gsumsq);
        hipLaunchKernelGGL(bn_lrelu_f32_kernel, dim3(50000), dim3(256), 0, stream,
                           out, gsum, gsumsq, gamma, beta);
    }
}

// Round 6
// 527.782 us; speedup vs baseline: 1.1630x; 1.1630x over previous
//
#include <hip/hip_runtime.h>
#include <hip/hip_bf16.h>
#include <stdint.h>

#define N_PTS 400000
#define K_TAPS 9
#define CIN 128
#define COUT 128
#define EPS_BN 1e-4f
#define LEAK 0.333f

typedef __bf16 bf16x8 __attribute__((ext_vector_type(8)));
typedef float floatx16 __attribute__((ext_vector_type(16)));

// ws layout (bytes):
//   [0, 294912)              packed W (bf16) in B-fragment order
//   [294912, 295424)         gsum[128]   (float)
//   [295424, 295936)         gsumsq[128] (float)
//   [295936, 296960)         (pad)
//   -- Path A only --
//   [296960, ...)            feats_bf16 [N+1,128]  (row N_PTS = zeros, sentinel target)
//   [...,    ...)            prebn_bf16 [N,128]
#define PACKW_BYTES (K_TAPS * 8 * 4 * 64 * 8 * 2)  // 294912 (32768 B per tap)
#define SUMS_OFF PACKW_BYTES
#define SUMSQ_OFF (SUMS_OFF + 512)
#define AB_OFF (SUMSQ_OFF + 512)
#define FEATSB_OFF (AB_OFF + 1024)                               // 296960
#define PREBN_OFF (FEATSB_OFF + (size_t)(N_PTS + 1) * CIN * 2)   // feats + zero row
#define WS_NEED_A (PREBN_OFF + (size_t)N_PTS * COUT * 2)

// round-to-nearest (half away) fp32 -> bf16, packed pair
__device__ inline unsigned int pack_bf16_rn(float lo, float hi) {
    unsigned int a = __float_as_uint(lo) + 0x8000u;
    unsigned int b = __float_as_uint(hi) + 0x8000u;
    return (a >> 16) | (b & 0xffff0000u);
}

// async global->LDS, 16B per lane. LDS dest is wave-uniform base + lane*16.
__device__ inline void gload_lds16(const void* g, void* l) {
    __builtin_amdgcn_global_load_lds(
        (const __attribute__((address_space(1))) unsigned int*)g,
        (__attribute__((address_space(3))) unsigned int*)l, 16, 0, 0);
}

// fp32 feats -> bf16 (rn), 8 elems/thread: 2x float4 read (16B/lane stride,
// coalesced), ONE uint4 store (16B/lane stride, 1KB/wave contiguous).
// Extra block zeroes the sentinel row.
__global__ __launch_bounds__(256) void convert_feats_kernel(
    const float* __restrict__ f, __hip_bfloat16* __restrict__ o) {
    if (blockIdx.x == 25000) {  // zero row at index N_PTS (gather target for missing nbrs)
        if (threadIdx.x < 16) {
            uint4 z = {0u, 0u, 0u, 0u};
            *(uint4*)(o + (size_t)N_PTS * CIN + threadIdx.x * 8) = z;
        }
        return;
    }
    size_t i = ((size_t)blockIdx.x * 256 + threadIdx.x) * 8;
    const float4* f4 = (const float4*)(f + i);
    float4 a = f4[0], b = f4[1];
    uint4 v;
    v.x = pack_bf16_rn(a.x, a.y);
    v.y = pack_bf16_rn(a.z, a.w);
    v.z = pack_bf16_rn(b.x, b.y);
    v.w = pack_bf16_rn(b.z, b.w);
    *(uint4*)(o + i) = v;
}

// Pack W[k][ci][co] (fp32) into bf16 MFMA B-fragment order:
// packw[frag=((k*8+c)*4+t)][lane*8+j] = W[k][c*16 + (lane>>5)*8 + j][t*32 + (lane&31)]
// Block 288 zeroes gsum[128]+gsumsq[128].
__global__ void pack_w_kernel(const float* __restrict__ W,
                              __hip_bfloat16* __restrict__ pw,
                              float* __restrict__ gsum) {
    if (blockIdx.x == 288) {
        ((float4*)gsum)[threadIdx.x] = make_float4(0.f, 0.f, 0.f, 0.f);
        return;
    }
    int frag = blockIdx.x;  // 0..287
    int lane = threadIdx.x; // 0..63
    int t = frag & 3;
    int c = (frag >> 2) & 7;
    int k = frag >> 5;
    int n = lane & 31;
    int kk0 = (lane >> 5) * 8;
    const float* src = W + (size_t)k * CIN * COUT + (size_t)(c * 16 + kk0) * COUT + (t * 32 + n);
    __hip_bfloat16* dst = pw + (size_t)frag * 512 + lane * 8;
#pragma unroll
    for (int j = 0; j < 8; ++j) dst[j] = (__hip_bfloat16)src[(size_t)j * COUT];
}

// Stage one tap's packed W (32 KB) into LDS buffer buf via async global_load_lds.
// 8 waves x 4 chunks x (64 lanes x 16B) = 32 KB, linear layout.
__device__ inline void stage_tap(char* smem, const char* pwb, int k, int buf,
                                 int wave, int lane) {
    const char* g = pwb + (size_t)k * 32768;
    char* l = smem + buf * 32768;
#pragma unroll
    for (int i = 0; i < 4; ++i) {
        int chunk = i * 8 + wave;
        gload_lds16(g + (size_t)chunk * 1024 + (size_t)lane * 16, l + (size_t)chunk * 1024);
    }
}

// Main gather-GEMM. Grid: 1563 x 512. WG tile: 256 rows x 128 cout (8 waves).
// Wave w: rows [blk*256 + w*32, +32) x 128 cout via 4 n-tiles of 32x32x16 MFMA.
//
// Counted-vmcnt pipeline (bf16 path), per tap k:
//   [load nb(k+2): 1 vmem]  [stage W(k+1): 4 global_load_lds]  (sched fence)
//   [32 MFMA over tap k, interleaved with 8 in-place gathers of tap k+1's A rows]
//   (sched fence)  s_waitcnt vmcnt(8)  -> nb+stage retired, 8 gathers STAY IN FLIGHT
//   s_barrier      -> W(k+1) visible to all waves; gathers complete under next MFMAs.
// No vmcnt(0) drain in the loop (T4); av[] reused in place (no reg growth, no spill).
// Missing neighbors gather from the zeroed sentinel row (no cndmask in inner loop).
template <bool GATHER_BF16, bool OUT_BF16>
__global__ __launch_bounds__(512, 4) void spconv_gemm_kernel(
    const void* __restrict__ feats_any,
    const __hip_bfloat16* __restrict__ packw,
    const int* __restrict__ neigh,
    void* __restrict__ out_any,
    float* __restrict__ gsum, float* __restrict__ gsumsq) {
    __shared__ __align__(16) char smem[65536];

    const int tid = threadIdx.x;
    const int wave = tid >> 6;
    const int lane = tid & 63;
    const int hj = lane >> 5;
    const int m = lane & 31;
    const int row = blockIdx.x * 256 + wave * 32 + m;
    const bool rvalid = (row < N_PTS);
    const size_t nbase = (size_t)row * K_TAPS;

    floatx16 acc[4];
#pragma unroll
    for (int t = 0; t < 4; ++t)
#pragma unroll
        for (int r = 0; r < 16; ++r) acc[t][r] = 0.0f;

    const char* pwb = (const char*)packw;

    if constexpr (GATHER_BF16) {
        const __hip_bfloat16* fb = (const __hip_bfloat16*)feats_any;
        uint4 av[8];     // A fragments of the CURRENT tap; overwritten in place for next
        int nbA, nbB;    // rolling neighbor ids: slot (k&1) holds nb[k]

        // prologue: nb[0], nb[1]; stage W(0); gather tap-0 A; counted wait; barrier
        nbA = rvalid ? neigh[nbase + 0] : N_PTS;
        nbB = rvalid ? neigh[nbase + 1] : N_PTS;
        stage_tap(smem, pwb, 0, 0, wave, lane);
        __builtin_amdgcn_sched_barrier(0);
        {
            const uint4* ar = (const uint4*)(fb + (size_t)nbA * CIN);
#pragma unroll
            for (int c = 0; c < 8; ++c) av[c] = ar[c * 2 + hj];
        }
        __builtin_amdgcn_sched_barrier(0);
        asm volatile("s_waitcnt vmcnt(8)" ::: "memory");  // nb+stage done; gathers fly
        __builtin_amdgcn_s_barrier();

#pragma unroll
        for (int k = 0; k < K_TAPS; ++k) {
            const int cur = k & 1;
            // rolling nb prefetch for tap k+2 into the slot of (dead) nb[k]
            if (k + 2 < K_TAPS) {
                int v = rvalid ? neigh[nbase + k + 2] : N_PTS;
                if (cur == 0) nbA = v; else nbB = v;
            }
            if (k + 1 < K_TAPS) stage_tap(smem, pwb, k + 1, cur ^ 1, wave, lane);
            __builtin_amdgcn_sched_barrier(0);

            const char* bbase = smem + (size_t)cur * 32768;
            const int nbn = (cur == 0) ? nbB : nbA;  // nb[k+1]
            const uint4* arn = (const uint4*)(fb + (size_t)nbn * CIN);

            __builtin_amdgcn_s_setprio(1);
#pragma unroll
            for (int c = 0; c < 8; ++c) {
                bf16x8 afrag = __builtin_bit_cast(bf16x8, av[c]);
#pragma unroll
                for (int t = 0; t < 4; ++t) {
                    bf16x8 bfrag = __builtin_bit_cast(
                        bf16x8, *(const uint4*)(bbase + (c * 4 + t) * 1024 + lane * 16));
                    acc[t] = __builtin_amdgcn_mfma_f32_32x32x16_bf16(afrag, bfrag, acc[t], 0, 0, 0);
                }
                if (k + 1 < K_TAPS) av[c] = arn[c * 2 + hj];  // in-place prefetch, tap k+1
            }
            __builtin_amdgcn_s_setprio(0);
            __builtin_amdgcn_sched_barrier(0);

            if (k + 1 < K_TAPS) {
                // retire nb(k+2)+stage(k+1) (oldest 5); the 8 gathers of tap k+1 remain
                // outstanding ACROSS the barrier and finish under the next MFMA phase.
                asm volatile("s_waitcnt vmcnt(8)" ::: "memory");
                __builtin_amdgcn_s_barrier();
            }
        }
    } else {
        // fp32 fallback path (round-1 structure: gather in-tap, full barriers)
        int nb[K_TAPS];
#pragma unroll
        for (int k = 0; k < K_TAPS; ++k)
            nb[k] = rvalid ? neigh[nbase + k] : N_PTS;
        stage_tap(smem, pwb, 0, 0, wave, lane);
        __syncthreads();
#pragma unroll
        for (int k = 0; k < K_TAPS; ++k) {
            const int cur = k & 1;
            const bool valid = (nb[k] < N_PTS);
            const int safe = valid ? nb[k] : 0;
            uint4 a8[8];
            const float4* ar = (const float4*)((const float*)feats_any + (size_t)safe * CIN);
#pragma unroll
            for (int c = 0; c < 8; ++c) {
                float4 f0 = ar[c * 4 + hj * 2];
                float4 f1 = ar[c * 4 + hj * 2 + 1];
                a8[c].x = pack_bf16_rn(f0.x, f0.y);
                a8[c].y = pack_bf16_rn(f0.z, f0.w);
                a8[c].z = pack_bf16_rn(f1.x, f1.y);
                a8[c].w = pack_bf16_rn(f1.z, f1.w);
            }
            if (k + 1 < K_TAPS) stage_tap(smem, pwb, k + 1, cur ^ 1, wave, lane);
            if (!valid) {
#pragma unroll
                for (int c = 0; c < 8; ++c) { a8[c].x = 0u; a8[c].y = 0u; a8[c].z = 0u; a8[c].w = 0u; }
            }
            const char* bbase = smem + (size_t)cur * 32768;
#pragma unroll
            for (int c = 0; c < 8; ++c) {
                bf16x8 afrag = __builtin_bit_cast(bf16x8, a8[c]);
#pragma unroll
                for (int t = 0; t < 4; ++t) {
                    bf16x8 bfrag = __builtin_bit_cast(
                        bf16x8, *(const uint4*)(bbase + (c * 4 + t) * 1024 + lane * 16));
                    acc[t] = __builtin_amdgcn_mfma_f32_32x32x16_bf16(afrag, bfrag, acc[t], 0, 0, 0);
                }
            }
            __syncthreads();
        }
    }

    __syncthreads();  // full drain; smem reused below

    // ---- epilogue: store pre-BN, accumulate channel sums ----
    // C/D layout (32x32): col = lane&31, row = (reg&3) + 8*(reg>>2) + 4*(lane>>5)
#pragma unroll
    for (int t = 0; t < 4; ++t) {
#pragma unroll
        for (int r = 0; r < 16; ++r) {
            int row_local = (r & 3) + 8 * (r >> 2) + 4 * hj;
            size_t grow = (size_t)blockIdx.x * 256 + wave * 32 + row_local;
            if (grow < N_PTS) {
                if (OUT_BF16)
                    ((__hip_bfloat16*)out_any)[grow * COUT + (t * 32 + m)] =
                        (__hip_bfloat16)acc[t][r];
                else
                    ((float*)out_any)[grow * COUT + (t * 32 + m)] = acc[t][r];
            }
        }
    }

    float s[4], q[4];
#pragma unroll
    for (int t = 0; t < 4; ++t) {
        s[t] = 0.0f; q[t] = 0.0f;
#pragma unroll
        for (int r = 0; r < 16; ++r) {
            float v = acc[t][r];
            s[t] += v;
            q[t] += v * v;
        }
        s[t] += __shfl_xor(s[t], 32, 64);
        q[t] += __shfl_xor(q[t], 32, 64);
    }

    float* lsum = (float*)smem;           // [8][128]
    float* lsq = (float*)(smem + 4096);   // [8][128]
    if (hj == 0) {
#pragma unroll
        for (int t = 0; t < 4; ++t) {
            lsum[wave * 128 + t * 32 + m] = s[t];
            lsq[wave * 128 + t * 32 + m] = q[t];
        }
    }
    __syncthreads();
    if (tid < 128) {
        float ts = 0.0f, tq = 0.0f;
#pragma unroll
        for (int w = 0; w < 8; ++w) {
            ts += lsum[w * 128 + tid];
            tq += lsq[w * 128 + tid];
        }
        atomicAdd(&gsum[tid], ts);
        atomicAdd(&gsumsq[tid], tq);
    }
}

// Path A BN: per-block ab in LDS (folds finalize_scales), 4 elems/thread.
// Read: uint2/lane (512B/wave contiguous). Write: ONE float4/lane
// (1KB/wave contiguous per instruction) — plain cached stores.
__global__ __launch_bounds__(256) void bn_lrelu_bf16_kernel(
    const __hip_bfloat16* __restrict__ pre, float* __restrict__ out,
    const float* __restrict__ gsum, const float* __restrict__ gsumsq,
    const float* __restrict__ gamma, const float* __restrict__ beta) {
    __shared__ float ab[256];
    const int tid = threadIdx.x;
    if (tid < 128) {
        const float inv_n = 1.0f / (float)N_PTS;
        float mean = gsum[tid] * inv_n;
        float var = gsumsq[tid] * inv_n - mean * mean;
        float a = gamma[tid] * rsqrtf(var + EPS_BN);
        ab[tid] = a;
        ab[128 + tid] = beta[tid] - mean * a;
    }
    __syncthreads();

    size_t i = ((size_t)blockIdx.x * 256 + tid) * 4;
    int c = (int)(i & (COUT - 1));
    uint2 v = *(const uint2*)(pre + i);
    float x0 = __uint_as_float((v.x & 0xffffu) << 16);
    float x1 = __uint_as_float((v.x >> 16) << 16);
    float x2 = __uint_as_float((v.y & 0xffffu) << 16);
    float x3 = __uint_as_float((v.y >> 16) << 16);
    float y0 = fmaf(ab[c], x0, ab[128 + c]);
    float y1 = fmaf(ab[c + 1], x1, ab[128 + c + 1]);
    float y2 = fmaf(ab[c + 2], x2, ab[128 + c + 2]);
    float y3 = fmaf(ab[c + 3], x3, ab[128 + c + 3]);
    float4 o;
    o.x = (y0 > 0.0f) ? y0 : LEAK * y0;
    o.y = (y1 > 0.0f) ? y1 : LEAK * y1;
    o.z = (y2 > 0.0f) ? y2 : LEAK * y2;
    o.w = (y3 > 0.0f) ? y3 : LEAK * y3;
    *(float4*)(out + i) = o;
}

// Path B: in-place fp32 BN + LeakyReLU, 4 elems/thread, per-block ab.
__global__ __launch_bounds__(256) void bn_lrelu_f32_kernel(
    float* __restrict__ out,
    const float* __restrict__ gsum, const float* __restrict__ gsumsq,
    const float* __restrict__ gamma, const float* __restrict__ beta) {
    __shared__ float ab[256];
    const int tid = threadIdx.x;
    if (tid < 128) {
        const float inv_n = 1.0f / (float)N_PTS;
        float mean = gsum[tid] * inv_n;
        float var = gsumsq[tid] * inv_n - mean * mean;
        float a = gamma[tid] * rsqrtf(var + EPS_BN);
        ab[tid] = a;
        ab[128 + tid] = beta[tid] - mean * a;
    }
    __syncthreads();

    size_t i = ((size_t)blockIdx.x * 256 + tid) * 4;
    int c = (int)(i & (COUT - 1));
    float4 v = *(const float4*)(out + i);
    v.x = fmaf(ab[c], v.x, ab[128 + c]);
    v.y = fmaf(ab[c + 1], v.y, ab[128 + c + 1]);
    v.z = fmaf(ab[c + 2], v.z, ab[128 + c + 2]);
    v.w = fmaf(ab[c + 3], v.w, ab[128 + c + 3]);
    v.x = (v.x > 0.0f) ? v.x : LEAK * v.x;
    v.y = (v.y > 0.0f) ? v.y : LEAK * v.y;
    v.z = (v.z > 0.0f) ? v.z : LEAK * v.z;
    v.w = (v.w > 0.0f) ? v.w : LEAK * v.w;
    *(float4*)(out + i) = v;
}

extern "C" void kernel_launch(void* const* d_in, const int* in_sizes, int n_in,
                              void* d_out, int out_size, void* d_ws, size_t ws_size,
                              hipStream_t stream) {
    const float* feats = (const float*)d_in[0];
    const float* W = (const float*)d_in[1];
    // d_in[2] = bias: cancels exactly under BatchNorm (out - mean removes per-channel constants)
    const float* gamma = (const float*)d_in[3];
    const float* beta = (const float*)d_in[4];
    const int* neigh = (const int*)d_in[5];
    float* out = (float*)d_out;

    char* ws = (char*)d_ws;
    __hip_bfloat16* packw = (__hip_bfloat16*)ws;
    float* gsum = (float*)(ws + SUMS_OFF);
    float* gsumsq = (float*)(ws + SUMSQ_OFF);

    const int gemm_grid = (N_PTS + 255) / 256;  // 1563 (tail rows guarded)

    // pack_w grid 289: blocks 0..287 pack W, block 288 zeroes gsum+gsumsq
    hipLaunchKernelGGL(pack_w_kernel, dim3(289), dim3(64), 0, stream, W, packw, gsum);

    if (ws_size >= WS_NEED_A) {
        __hip_bfloat16* featsb = (__hip_bfloat16*)(ws + FEATSB_OFF);
        __hip_bfloat16* prebn = (__hip_bfloat16*)(ws + PREBN_OFF);
        // grid 25001: block 25000 zeroes the sentinel row N_PTS
        hipLaunchKernelGGL(convert_feats_kernel, dim3(25001), dim3(256), 0, stream, feats, featsb);
        hipLaunchKernelGGL((spconv_gemm_kernel<true, true>), dim3(gemm_grid), dim3(512), 0,
                           stream, (const void*)featsb, packw, neigh, (void*)prebn, gsum, gsumsq);
        hipLaunchKernelGGL(bn_lrelu_bf16_kernel, dim3(50000), dim3(256), 0, stream,
                           prebn, out, gsum, gsumsq, gamma, beta);
    } else {
        hipLaunchKernelGGL((spconv_gemm_kernel<false, false>), dim3(gemm_grid), dim3(512), 0,
                           stream, (const void*)feats, packw, neigh, (void*)out, gsum, gsumsq);
        hipLaunchKernelGGL(bn_lrelu_f32_kernel, dim3(100000), dim3(256), 0, stream,
                           out, gsum, gsumsq, gamma, beta);
    }
}